// Round 2
// baseline (577.320 us; speedup 1.0000x reference)
//
#include <hip/hip_runtime.h>
#include <hip/hip_bf16.h>

#define NB 4
#define CH 256
#define HH 64
#define WW 64
#define NPIX 4096      // HH*WW
#define OH 62
#define NPATCH 3844    // 62*62
#define KDIM 256       // == CH
#define EPSN 1e-12f

typedef __attribute__((ext_vector_type(8))) short short8;
typedef __attribute__((ext_vector_type(4))) float f32x4;

// ---------------- K1: per-pixel channel sum-of-squares + inverse norms ----------------
__global__ void k_norms(const float* __restrict__ pred, const float* __restrict__ tgt,
                        float* __restrict__ ssP, float* __restrict__ invP,
                        float* __restrict__ ssT, float* __restrict__ invT) {
    int tid = blockIdx.x * 256 + threadIdx.x;      // 0..16383  (b*4096 + pix)
    int b = tid >> 12, pix = tid & 4095;
    const float* p = pred + (size_t)b * CH * NPIX + pix;
    const float* t = tgt  + (size_t)b * CH * NPIX + pix;
    float sp = 0.f, st = 0.f;
    for (int c = 0; c < CH; ++c) { float v = p[(size_t)c * NPIX]; sp += v * v; }
    for (int c = 0; c < CH; ++c) { float v = t[(size_t)c * NPIX]; st += v * v; }
    ssP[tid] = sp; invP[tid] = 1.f / fmaxf(sqrtf(sp), EPSN);
    ssT[tid] = st; invT[tid] = 1.f / fmaxf(sqrtf(st), EPSN);
}

// ------------- K2: normalize + transpose (C,pix)->(pix,C) + bf16 cast -------------
__global__ void k_transpose(const float* __restrict__ pred, const float* __restrict__ tgt,
                            const float* __restrict__ invP, const float* __restrict__ invT,
                            __hip_bfloat16* __restrict__ Xn, __hip_bfloat16* __restrict__ Tn) {
    int bz = blockIdx.z;                 // 0..7: (b, which)
    int b = bz >> 1, which = bz & 1;
    const float* src = which ? tgt : pred;
    const float* inv = which ? invT : invP;
    __hip_bfloat16* dst = which ? Tn : Xn;
    src += (size_t)b * CH * NPIX;
    inv += (size_t)b * NPIX;
    dst += (size_t)b * NPIX * CH;
    int pix0 = blockIdx.x * 64, c0 = blockIdx.y * 64;
    __shared__ float tile[64][65];       // +1 pad: conflict-free transpose
    int tx = threadIdx.x & 63, ty = threadIdx.x >> 6;
#pragma unroll
    for (int r = 0; r < 16; ++r) {
        int cc = ty + r * 4;
        tile[cc][tx] = src[(size_t)(c0 + cc) * NPIX + pix0 + tx];
    }
    __syncthreads();
#pragma unroll
    for (int r = 0; r < 16; ++r) {
        int pp = ty + r * 4;
        float v = tile[tx][pp] * inv[pix0 + pp];
        dst[(size_t)(pix0 + pp) * CH + c0 + tx] = __float2bfloat16(v);
    }
}

// ---------------- K3: D = Xn * Tn^T  (4096x4096 f32, K=256, bf16 MFMA) ----------------
__device__ __forceinline__ void gload_lds16(const void* g, void* l) {
    __builtin_amdgcn_global_load_lds(
        (const __attribute__((address_space(1))) void*)g,
        (__attribute__((address_space(3))) void*)l, 16, 0, 0);
}

__global__ __launch_bounds__(256) void k_gemm(const __hip_bfloat16* __restrict__ A,
                                              const __hip_bfloat16* __restrict__ Bm,
                                              float* __restrict__ D) {
    __shared__ short As[128 * 32];   // [row][k] bf16, row stride 32 (64B)
    __shared__ short Bs[128 * 32];
    const int t = threadIdx.x;
    const int lane = t & 63, wv = t >> 6;
    const int wm = wv >> 1, wn = wv & 1;           // 2x2 wave grid, 64x64 each
    const int row0 = blockIdx.y * 128, col0 = blockIdx.x * 128;
    const short* Ag = (const short*)A;
    const short* Bg = (const short*)Bm;
    const int srow = t >> 2;                        // staging row within 64-row chunk
    const int kch  = (t & 3) * 8;                   // staging k element offset (8 bf16 = 16B)

    f32x4 acc[4][4] = {};

    for (int k0 = 0; k0 < KDIM; k0 += 32) {
        gload_lds16(Ag + (size_t)(row0 + srow) * KDIM + k0 + kch,      As + wv * 512);
        gload_lds16(Ag + (size_t)(row0 + 64 + srow) * KDIM + k0 + kch, As + 2048 + wv * 512);
        gload_lds16(Bg + (size_t)(col0 + srow) * KDIM + k0 + kch,      Bs + wv * 512);
        gload_lds16(Bg + (size_t)(col0 + 64 + srow) * KDIM + k0 + kch, Bs + 2048 + wv * 512);
        __syncthreads();

        const int rsel = lane & 15, ksel = (lane >> 4) * 8;
        short8 a[4], bfr[4];
#pragma unroll
        for (int mi = 0; mi < 4; ++mi)
            a[mi] = *(const short8*)&As[(wm * 64 + mi * 16 + rsel) * 32 + ksel];
#pragma unroll
        for (int ni = 0; ni < 4; ++ni)
            bfr[ni] = *(const short8*)&Bs[(wn * 64 + ni * 16 + rsel) * 32 + ksel];
#pragma unroll
        for (int mi = 0; mi < 4; ++mi)
#pragma unroll
            for (int ni = 0; ni < 4; ++ni)
                acc[mi][ni] = __builtin_amdgcn_mfma_f32_16x16x32_bf16(a[mi], bfr[ni], acc[mi][ni], 0, 0, 0);
        __syncthreads();
    }
    const int rbase = (lane >> 4) * 4, cbase = lane & 15;
#pragma unroll
    for (int mi = 0; mi < 4; ++mi) {
#pragma unroll
        for (int ni = 0; ni < 4; ++ni) {
            int r0 = row0 + wm * 64 + mi * 16 + rbase;
            int c  = col0 + wn * 64 + ni * 16 + cbase;
#pragma unroll
            for (int r = 0; r < 4; ++r)
                D[(size_t)(r0 + r) * NPIX + c] = acc[mi][ni][r];
        }
    }
}

// ------------- K4: diagonal-tile argmax.  S[q,p] lives on diagonal y-x = qpix-ppix. -------------
// Grid (62 qr, 8). 4 waves/block; wave slot w = blockIdx.y*4 + wv owns pr = {w, w+32}.
// Per (qr,pr): lane=pc accumulates a[m] = sum_i D[(qr+i)*64+m, (pr+i)*64+pc] (192 coalesced loads),
// then s[qc] = a[qc] + shfl(a[qc+1],1) + shfl(a[qc+2],2). Best kept as packed key:
// (monotone-f32 & 0xFFFFF000) | (63-pr)<<6 | (63-pc)  -> max == (value desc, pr asc, pc asc).
__global__ __launch_bounds__(256) void k_argmax(const float* __restrict__ D,
                                                unsigned* __restrict__ part) {
    const int qr = blockIdx.x;
    const int t = threadIdx.x, lane = t & 63, wv = t >> 6;
    const int wslot = blockIdx.y * 4 + wv;          // 0..31
    const bool vlane = lane < OH;

    unsigned best[OH];
#pragma unroll
    for (int qc = 0; qc < OH; ++qc) best[qc] = 0u;

    for (int pr = wslot; pr < OH; pr += 32) {
        float a[64];
#pragma unroll
        for (int m = 0; m < 64; ++m) a[m] = 0.f;
#pragma unroll
        for (int i = 0; i < 3; ++i) {
            const float* col = D + (size_t)((qr + i) * 64) * NPIX + (pr + i) * 64 + lane;
#pragma unroll
            for (int m = 0; m < 64; ++m)
                a[m] += col[(size_t)m * NPIX];
        }
        const unsigned prk = ((unsigned)(63 - pr) << 6) | (unsigned)(63 - lane);
#pragma unroll
        for (int qc = 0; qc < OH; ++qc) {
            float s = a[qc] + __shfl_down(a[qc + 1], 1, 64) + __shfl_down(a[qc + 2], 2, 64);
            unsigned u = __float_as_uint(s);
            u = (s >= 0.f) ? (u | 0x80000000u) : ~u;
            unsigned key = (u & 0xFFFFF000u) | prk;
            key = vlane ? key : 0u;
            if (key > best[qc]) best[qc] = key;
        }
    }
    // butterfly max over 64 lanes, per qc
#pragma unroll
    for (int qc = 0; qc < OH; ++qc) {
        unsigned k = best[qc];
#pragma unroll
        for (int d = 1; d < 64; d <<= 1) {
            unsigned o = __shfl_xor(k, d, 64);
            k = o > k ? o : k;
        }
        best[qc] = k;
    }
    if (lane == 0) {
        unsigned* dst = part + ((size_t)qr * 32 + wslot) * OH;
#pragma unroll
        for (int qc = 0; qc < OH; ++qc) dst[qc] = best[qc];
    }
}

// -------- K5: fold 32 partial keys -> match; loss via norm expansion --------
__global__ void k_loss(const float* __restrict__ D, const unsigned* __restrict__ part,
                       const float* __restrict__ ssP, const float* __restrict__ invP,
                       const float* __restrict__ ssT, const float* __restrict__ invT,
                       float* __restrict__ out) {
    int q = blockIdx.x * 256 + threadIdx.x;
    float acc = 0.f;
    if (q < NPATCH) {
        int qr = q / OH, qc = q - qr * OH;
        int qpix = qr * WW + qc;
        unsigned key = 0u;
#pragma unroll
        for (int w = 0; w < 32; ++w) {
            unsigned k = part[((size_t)qr * 32 + w) * OH + qc];
            key = k > key ? k : key;
        }
        int mpr = 63 - ((key >> 6) & 63);
        int mpc = 63 - (key & 63);
        int mpix = mpr * WW + mpc;
#pragma unroll
        for (int i = 0; i < 3; ++i)
#pragma unroll
            for (int j = 0; j < 3; ++j) {
                int off = i * WW + j;
                int y = qpix + off, x = mpix + off;
                float nP = ssP[y] * invP[y];   // = ||p_y||
                float nT = ssT[x] * invT[x];
                acc += ssP[y] + ssT[x] - 2.f * D[(size_t)y * NPIX + x] * nP * nT;
            }
    }
#pragma unroll
    for (int s = 32; s > 0; s >>= 1) acc += __shfl_down(acc, s, 64);
    if ((threadIdx.x & 63) == 0)
        atomicAdd(out, acc * (1.f / 35426304.f));   // / (4*3844*2304)
}

// ---------------------------------- launch ----------------------------------
extern "C" void kernel_launch(void* const* d_in, const int* in_sizes, int n_in,
                              void* d_out, int out_size, void* d_ws, size_t ws_size,
                              hipStream_t stream) {
    const float* pred = (const float*)d_in[0];
    const float* tgt  = (const float*)d_in[1];
    char* ws = (char*)d_ws;
    // ws layout (bytes): D 64MB | Xn 8MB | Tn 8MB | ssP/invP/ssT/invT 64KB ea | part 492KB
    float*          Dws  = (float*)(ws);
    __hip_bfloat16* Xn   = (__hip_bfloat16*)(ws + 67108864);
    __hip_bfloat16* Tn   = (__hip_bfloat16*)(ws + 75497472);
    float*          ssP  = (float*)(ws + 83886080);
    float*          invP = (float*)(ws + 83951616);
    float*          ssT  = (float*)(ws + 84017152);
    float*          invT = (float*)(ws + 84082688);
    unsigned*       part = (unsigned*)(ws + 84148224);

    hipMemsetAsync(d_out, 0, sizeof(float), stream);
    k_norms<<<64, 256, 0, stream>>>(pred, tgt, ssP, invP, ssT, invT);
    k_transpose<<<dim3(64, 4, 8), 256, 0, stream>>>(pred, tgt, invP, invT, Xn, Tn);
    for (int b = 0; b < NB; ++b) {
        const __hip_bfloat16* Ab = Xn + (size_t)b * NPIX * CH;
        const __hip_bfloat16* Bb = Tn + (size_t)b * NPIX * CH;
        k_gemm<<<dim3(32, 32), 256, 0, stream>>>(Ab, Bb, Dws);
        k_argmax<<<dim3(62, 8), 256, 0, stream>>>(Dws, part);
        k_loss<<<16, 256, 0, stream>>>(Dws, part,
                                       ssP + b * NPIX, invP + b * NPIX,
                                       ssT + b * NPIX, invT + b * NPIX,
                                       (float*)d_out);
    }
}

// Round 3
// 436.271 us; speedup vs baseline: 1.3233x; 1.3233x over previous
//
#include <hip/hip_runtime.h>
#include <hip/hip_bf16.h>

#define NB 4
#define CH 256
#define HH 64
#define WW 64
#define NPIX 4096      // HH*WW
#define OH 62
#define NPATCH 3844    // 62*62
#define KDIM 256       // == CH
#define EPSN 1e-12f

typedef __attribute__((ext_vector_type(8))) short short8;
typedef __attribute__((ext_vector_type(4))) float f32x4;

__device__ __forceinline__ float bf16_to_f32(unsigned short u) {
    return __uint_as_float((unsigned)u << 16);
}
__device__ __forceinline__ unsigned short f32_to_bf16(float f) {
    __hip_bfloat16 h = __float2bfloat16(f);
    return *(unsigned short*)&h;
}

// ---- K1 (fused prep): read inputs ONCE; per-pixel ss + inv-norm; normalized bf16
// ---- transpose (C,pix)->(pix,C).  Grid (64 pixtiles, 8 = b*2+which), 256 thr.
__global__ __launch_bounds__(256) void k_prep(const float* __restrict__ pred,
                                              const float* __restrict__ tgt,
                                              __hip_bfloat16* __restrict__ Xn,
                                              __hip_bfloat16* __restrict__ Tn,
                                              float* __restrict__ ssP, float* __restrict__ invP,
                                              float* __restrict__ ssT, float* __restrict__ invT) {
    const int bz = blockIdx.y;            // 0..7
    const int b = bz >> 1, which = bz & 1;
    const float* src = (which ? tgt : pred) + (size_t)b * CH * NPIX;
    unsigned short* dst = (unsigned short*)((which ? Tn : Xn) + (size_t)b * NPIX * CH);
    float* ss_g  = (which ? ssT  : ssP)  + b * NPIX;
    float* inv_g = (which ? invT : invP) + b * NPIX;
    const int pix0 = blockIdx.x * 64;
    const int t = threadIdx.x, lane = t & 63, wv = t >> 6;

    __shared__ unsigned short stage[CH][65];   // bf16, +1 pad
    __shared__ float partial[4][64];
    __shared__ float inv_s[64];

    // load: wave wv covers c in [wv*64, wv*64+64); lane = pixel. f32 ss, bf16 stage.
    float ssacc = 0.f;
#pragma unroll 8
    for (int cc = 0; cc < 64; ++cc) {
        int c = wv * 64 + cc;
        float v = src[(size_t)c * NPIX + pix0 + lane];
        ssacc += v * v;
        stage[c][lane] = f32_to_bf16(v);
    }
    partial[wv][lane] = ssacc;
    __syncthreads();
    if (t < 64) {
        float ss = partial[0][t] + partial[1][t] + partial[2][t] + partial[3][t];
        float inv = 1.f / fmaxf(sqrtf(ss), EPSN);
        ss_g[pix0 + t] = ss;
        inv_g[pix0 + t] = inv;
        inv_s[t] = inv;
    }
    __syncthreads();
    // write: wave wv handles pixels p = wv, wv+4, ...; lane = channel within 64-chunk.
    for (int p = wv; p < 64; p += 4) {
        float iv = inv_s[p];
#pragma unroll
        for (int cb = 0; cb < 4; ++cb) {
            int c = cb * 64 + lane;
            float v = bf16_to_f32(stage[c][p]) * iv;
            dst[(size_t)(pix0 + p) * CH + c] = f32_to_bf16(v);
        }
    }
}

// ---------------- K2: D = Xn * Tn^T  (4096x4096, K=256, bf16 MFMA, bf16 OUTPUT) ----------------
__device__ __forceinline__ void gload_lds16(const void* g, void* l) {
    __builtin_amdgcn_global_load_lds(
        (const __attribute__((address_space(1))) void*)g,
        (__attribute__((address_space(3))) void*)l, 16, 0, 0);
}

__global__ __launch_bounds__(256) void k_gemm(const __hip_bfloat16* __restrict__ A,
                                              const __hip_bfloat16* __restrict__ Bm,
                                              unsigned short* __restrict__ D) {
    __shared__ short As[128 * 32];   // [row][k] bf16, row stride 32 (64B)
    __shared__ short Bs[128 * 32];
    const int t = threadIdx.x;
    const int lane = t & 63, wv = t >> 6;
    const int wm = wv >> 1, wn = wv & 1;           // 2x2 wave grid, 64x64 each
    const int row0 = blockIdx.y * 128, col0 = blockIdx.x * 128;
    const short* Ag = (const short*)A;
    const short* Bg = (const short*)Bm;
    const int srow = t >> 2;
    const int kch  = (t & 3) * 8;

    f32x4 acc[4][4] = {};

    for (int k0 = 0; k0 < KDIM; k0 += 32) {
        gload_lds16(Ag + (size_t)(row0 + srow) * KDIM + k0 + kch,      As + wv * 512);
        gload_lds16(Ag + (size_t)(row0 + 64 + srow) * KDIM + k0 + kch, As + 2048 + wv * 512);
        gload_lds16(Bg + (size_t)(col0 + srow) * KDIM + k0 + kch,      Bs + wv * 512);
        gload_lds16(Bg + (size_t)(col0 + 64 + srow) * KDIM + k0 + kch, Bs + 2048 + wv * 512);
        __syncthreads();

        const int rsel = lane & 15, ksel = (lane >> 4) * 8;
        short8 a[4], bfr[4];
#pragma unroll
        for (int mi = 0; mi < 4; ++mi)
            a[mi] = *(const short8*)&As[(wm * 64 + mi * 16 + rsel) * 32 + ksel];
#pragma unroll
        for (int ni = 0; ni < 4; ++ni)
            bfr[ni] = *(const short8*)&Bs[(wn * 64 + ni * 16 + rsel) * 32 + ksel];
#pragma unroll
        for (int mi = 0; mi < 4; ++mi)
#pragma unroll
            for (int ni = 0; ni < 4; ++ni)
                acc[mi][ni] = __builtin_amdgcn_mfma_f32_16x16x32_bf16(a[mi], bfr[ni], acc[mi][ni], 0, 0, 0);
        __syncthreads();
    }
    // C/D layout: col = lane&15, row = (lane>>4)*4 + reg
    const int rbase = (lane >> 4) * 4, cbase = lane & 15;
#pragma unroll
    for (int mi = 0; mi < 4; ++mi) {
#pragma unroll
        for (int ni = 0; ni < 4; ++ni) {
            int r0 = row0 + wm * 64 + mi * 16 + rbase;
            int c  = col0 + wn * 64 + ni * 16 + cbase;
#pragma unroll
            for (int r = 0; r < 4; ++r)
                D[(size_t)(r0 + r) * NPIX + c] = f32_to_bf16(acc[mi][ni][r]);
        }
    }
}

// ---- K3: R1-structure argmax over bf16 D + fused loss tail.
// One block per q (grid 62x62). Lane = pc, wave = pr stripe. No shuffles in hot loop.
__global__ __launch_bounds__(256) void k_argmax_loss(
        const unsigned short* __restrict__ D,
        const float* __restrict__ ssP, const float* __restrict__ invP,
        const float* __restrict__ ssT, const float* __restrict__ invT,
        float* __restrict__ out) {
    const int qc = blockIdx.x, qr = blockIdx.y;
    const int qpix = qr * WW + qc;
    const int t = threadIdx.x, lane = t & 63, ty = t >> 6;
    const unsigned short* Dr[9];
#pragma unroll
    for (int i = 0; i < 3; ++i)
#pragma unroll
        for (int j = 0; j < 3; ++j) {
            int off = i * WW + j;
            Dr[i * 3 + j] = D + (size_t)(qpix + off) * NPIX + off;
        }
    float best = -1e30f; int bidx = 0x7fffffff;
    if (lane < OH) {
        for (int pr = ty; pr < OH; pr += 4) {
            int pbase = pr * WW + lane;
            float s = 0.f;
#pragma unroll
            for (int k = 0; k < 9; ++k) s += bf16_to_f32(Dr[k][pbase]);
            int p = pr * OH + lane;
            if (s > best || (s == best && p < bidx)) { best = s; bidx = p; }
        }
    }
    __shared__ float sS[256];
    __shared__ int   sI[256];
    sS[t] = best; sI[t] = bidx;
    __syncthreads();
    for (int stride = 128; stride > 0; stride >>= 1) {
        if (t < stride) {
            float so = sS[t + stride]; int io = sI[t + stride];
            if (so > sS[t] || (so == sS[t] && io < sI[t])) { sS[t] = so; sI[t] = io; }
        }
        __syncthreads();
    }
    if (t == 0) {
        int m = sI[0];
        int mr = m / OH, mc = m - mr * OH;
        int mpix = mr * WW + mc;
        float acc = 0.f;
#pragma unroll
        for (int i = 0; i < 3; ++i)
#pragma unroll
            for (int j = 0; j < 3; ++j) {
                int off = i * WW + j;
                int y = qpix + off, x = mpix + off;
                float Dv = bf16_to_f32(D[(size_t)y * NPIX + x]);
                float nP = ssP[y] * invP[y];   // = ||p_y||
                float nT = ssT[x] * invT[x];
                acc += ssP[y] + ssT[x] - 2.f * Dv * nP * nT;
            }
        atomicAdd(out, acc * (1.f / 35426304.f));   // / (4*3844*2304)
    }
}

// ---------------------------------- launch ----------------------------------
extern "C" void kernel_launch(void* const* d_in, const int* in_sizes, int n_in,
                              void* d_out, int out_size, void* d_ws, size_t ws_size,
                              hipStream_t stream) {
    const float* pred = (const float*)d_in[0];
    const float* tgt  = (const float*)d_in[1];
    char* ws = (char*)d_ws;
    // ws layout (bytes): D(bf16) 32MB | Xn 8MB | Tn 8MB | ssP/invP/ssT/invT 64KB ea
    unsigned short* Dws  = (unsigned short*)(ws);
    __hip_bfloat16* Xn   = (__hip_bfloat16*)(ws + 33554432);
    __hip_bfloat16* Tn   = (__hip_bfloat16*)(ws + 41943040);
    float*          ssP  = (float*)(ws + 50331648);
    float*          invP = (float*)(ws + 50397184);
    float*          ssT  = (float*)(ws + 50462720);
    float*          invT = (float*)(ws + 50528256);

    hipMemsetAsync(d_out, 0, sizeof(float), stream);
    k_prep<<<dim3(64, 8), 256, 0, stream>>>(pred, tgt, Xn, Tn, ssP, invP, ssT, invT);
    for (int b = 0; b < NB; ++b) {
        const __hip_bfloat16* Ab = Xn + (size_t)b * NPIX * CH;
        const __hip_bfloat16* Bb = Tn + (size_t)b * NPIX * CH;
        k_gemm<<<dim3(32, 32), 256, 0, stream>>>(Ab, Bb, Dws);
        k_argmax_loss<<<dim3(62, 62), 256, 0, stream>>>(Dws,
                                       ssP + b * NPIX, invP + b * NPIX,
                                       ssT + b * NPIX, invT + b * NPIX,
                                       (float*)d_out);
    }
}